// Round 4
// baseline (508.097 us; speedup 1.0000x reference)
//
#include <hip/hip_runtime.h>

#define N_NODES 20000
#define E_EDGES 320000
#define E2 (E_EDGES + N_NODES)
#define HID 256
#define SLOPE 0.2f

// ---------------------------------------------------------------- CSR build
__global__ __launch_bounds__(256) void k_init(int* __restrict__ deg, int* __restrict__ cursor) {
    int i = blockIdx.x * 256 + threadIdx.x;
    if (i < N_NODES) { deg[i] = 1; cursor[i] = 0; }   // deg starts at 1: self loop
}

__global__ __launch_bounds__(256) void k_degree(const int* __restrict__ dst, int* __restrict__ deg) {
    int e = blockIdx.x * 256 + threadIdx.x;
    if (e < E_EDGES) atomicAdd(&deg[dst[e]], 1);
}

// single-block exclusive scan over deg[N] -> off[N+1]; shfl-based wave scan
__global__ __launch_bounds__(1024) void k_scan(const int* __restrict__ deg, int* __restrict__ off) {
    __shared__ int wsum[16];
    const int tid  = threadIdx.x;
    const int wave = tid >> 6;
    const int lane = tid & 63;
    int carry = 0;
    for (int base = 0; base < N_NODES; base += 1024) {
        const int i = base + tid;
        const int v = (i < N_NODES) ? deg[i] : 0;
        // inclusive scan within wave
        int x = v;
        #pragma unroll
        for (int o = 1; o < 64; o <<= 1) {
            int t = __shfl_up(x, o);
            if (lane >= o) x += t;
        }
        if (lane == 63) wsum[wave] = x;
        __syncthreads();
        if (wave == 0 && lane < 16) {
            int y = wsum[lane];
            #pragma unroll
            for (int o = 1; o < 16; o <<= 1) {
                int t = __shfl_up(y, o);
                if (lane >= o) y += t;
            }
            wsum[lane] = y;
        }
        __syncthreads();
        const int wbase = (wave == 0) ? 0 : wsum[wave - 1];
        if (i < N_NODES) off[i] = carry + wbase + (x - v);   // exclusive
        carry += wsum[15];
        __syncthreads();   // protect wsum before next iteration's writes
    }
    if (tid == 0) off[N_NODES] = carry;   // == E2
}

__global__ __launch_bounds__(256) void k_fill(const int* __restrict__ srcA, const int* __restrict__ dstA,
                                              const int* __restrict__ off, int* __restrict__ cursor,
                                              int* __restrict__ csr_src) {
    int e = blockIdx.x * 256 + threadIdx.x;
    if (e >= E2) return;
    int s, d;
    if (e < E_EDGES) { s = srcA[e]; d = dstA[e]; }
    else             { s = d = e - E_EDGES; }        // self loop
    int pos = atomicAdd(&cursor[d], 1);
    csr_src[off[d] + pos] = s;
}

// ---------------------------------------------------------------- GEMM
// X[M,256] @ {Wl|Wr}[256,256] + {bl|br} -> xl[M,256], xr[M,256]
// BM=128, BN=64, BK=32, 256 threads, 8x4 micro-tile.
// grid = (ceil(M/128), 8); by<4 -> Wl quarter, else Wr quarter.
// Sized for occupancy: ~25.6KB LDS (6 blocks/CU), VGPR capped via
// __launch_bounds__(256,5); 1256 blocks fill 256 CUs ~5 deep.
__global__ __launch_bounds__(256, 5) void k_gemm(const float* __restrict__ X,
                                                 const float* __restrict__ Wl, const float* __restrict__ Wr,
                                                 const float* __restrict__ bl, const float* __restrict__ br,
                                                 float* __restrict__ xl, float* __restrict__ xr) {
    __shared__ float As[32][132];   // [k][m], padded
    __shared__ float Bs[32][68];    // [k][n], padded
    const int tid = threadIdx.x;
    const int m0  = blockIdx.x * 128;
    const int by  = blockIdx.y;
    const float* W    = (by < 4) ? Wl : Wr;
    const float* bias = (by < 4) ? bl : br;
    float*       C    = (by < 4) ? xl : xr;
    const int n0 = (by & 3) * 64;
    const int tx = tid & 15;        // output cols n0 + tx*4
    const int ty = tid >> 4;        // output rows ty*4 and ty*4+64
    // A staging: each thread loads 4 rows (ar+32i), one float4 of k
    const int ar = tid >> 3;        // 0..31
    const int ac = (tid & 7) * 4;   // 0..28
    // B staging: each thread loads 2 k-rows (bkr+16i), one float4 of n
    const int bkr = tid >> 4;       // 0..15
    const int bcc = (tid & 15) * 4; // 0..60

    float4 av[4], bv[2];
#define LOAD_TILE(K0)                                                               \
    _Pragma("unroll")                                                               \
    for (int i = 0; i < 4; ++i) {                                                   \
        int gm = m0 + ar + i * 32;                                                  \
        av[i] = (gm < N_NODES)                                                      \
            ? *(const float4*)&X[(size_t)gm * 256 + (K0) + ac]                      \
            : make_float4(0.f, 0.f, 0.f, 0.f);                                      \
    }                                                                               \
    _Pragma("unroll")                                                               \
    for (int i = 0; i < 2; ++i)                                                     \
        bv[i] = *(const float4*)&W[(size_t)((K0) + bkr + i * 16) * 256 + n0 + bcc];

    LOAD_TILE(0)
    float acc[8][4] = {};
    for (int k0 = 0; k0 < 256; k0 += 32) {
        __syncthreads();   // protect previous iteration's LDS reads
        #pragma unroll
        for (int i = 0; i < 4; ++i) {
            const int mm = ar + i * 32;
            As[ac + 0][mm] = av[i].x;
            As[ac + 1][mm] = av[i].y;
            As[ac + 2][mm] = av[i].z;
            As[ac + 3][mm] = av[i].w;
        }
        #pragma unroll
        for (int i = 0; i < 2; ++i)
            *(float4*)&Bs[bkr + i * 16][bcc] = bv[i];
        __syncthreads();
        if (k0 + 32 < 256) { LOAD_TILE(k0 + 32) }   // reg prefetch of next tile

        #pragma unroll
        for (int kk = 0; kk < 32; ++kk) {
            float a8[8], b4[4];
            *(float4*)&a8[0] = *(const float4*)&As[kk][ty * 4];
            *(float4*)&a8[4] = *(const float4*)&As[kk][ty * 4 + 64];
            *(float4*)&b4[0] = *(const float4*)&Bs[kk][tx * 4];
            #pragma unroll
            for (int i = 0; i < 8; ++i)
                #pragma unroll
                for (int j = 0; j < 4; ++j)
                    acc[i][j] = fmaf(a8[i], b4[j], acc[i][j]);
        }
    }
#undef LOAD_TILE

    float4 bb4 = *(const float4*)&bias[n0 + tx * 4];
    float bb[4] = {bb4.x, bb4.y, bb4.z, bb4.w};
    #pragma unroll
    for (int half = 0; half < 2; ++half) {
        #pragma unroll
        for (int i = 0; i < 4; ++i) {
            const int gm = m0 + half * 64 + ty * 4 + i;
            if (gm < N_NODES) {
                const int ai = half * 4 + i;
                float4 o;
                o.x = acc[ai][0] + bb[0];
                o.y = acc[ai][1] + bb[1];
                o.z = acc[ai][2] + bb[2];
                o.w = acc[ai][3] + bb[3];
                *(float4*)&C[(size_t)gm * 256 + n0 + tx * 4] = o;
            }
        }
    }
}

// ---------------------------------------------------------------- fused edge phase
// one 64-lane wave per node: online-softmax over incoming edges, aggregate,
// +bias +relu. lane l covers flat channels 4l..4l+3 (head = l>>4).
// 2-deep prefetch: index fetch for p+2 overlaps row gather for p+1.
__global__ __launch_bounds__(256) void k_edge(const float* __restrict__ xl, const float* __restrict__ xr,
                                              const float* __restrict__ att,
                                              const int* __restrict__ csr_src, const int* __restrict__ off,
                                              const float* __restrict__ bias,
                                              float* __restrict__ out) {
    const int node = (blockIdx.x * 256 + threadIdx.x) >> 6;
    const int l = threadIdx.x & 63;
    if (node >= N_NODES) return;

    const float4 w  = *(const float4*)&att[l * 4];
    const float4 xd = *(const float4*)&xr[(size_t)node * 256 + l * 4];
    const int beg = off[node], end = off[node + 1];   // end > beg (self loop)

    float m = -1e30f, ssum = 0.f;
    float4 acc = make_float4(0.f, 0.f, 0.f, 0.f);

    int j1 = csr_src[beg];
    float4 a_nxt = *(const float4*)&xl[(size_t)j1 * 256 + l * 4];
    int j2 = (beg + 1 < end) ? csr_src[beg + 1] : 0;

    for (int p = beg; p < end; ++p) {
        const float4 a = a_nxt;
        if (p + 1 < end)
            a_nxt = *(const float4*)&xl[(size_t)j2 * 256 + l * 4];
        if (p + 2 < end)
            j2 = csr_src[p + 2];

        float t = 0.f, u;
        u = a.x + xd.x; u = (u > 0.f) ? u : SLOPE * u; t = fmaf(u, w.x, t);
        u = a.y + xd.y; u = (u > 0.f) ? u : SLOPE * u; t = fmaf(u, w.y, t);
        u = a.z + xd.z; u = (u > 0.f) ? u : SLOPE * u; t = fmaf(u, w.z, t);
        u = a.w + xd.w; u = (u > 0.f) ? u : SLOPE * u; t = fmaf(u, w.w, t);
        t += __shfl_xor(t, 1);
        t += __shfl_xor(t, 2);
        t += __shfl_xor(t, 4);
        t += __shfl_xor(t, 8);     // 16-lane head-group dot over 64 channels

        const float nm = fmaxf(m, t);
        const float sc = __expf(m - nm);
        const float wp = __expf(t - nm);
        acc.x = fmaf(acc.x, sc, wp * a.x);
        acc.y = fmaf(acc.y, sc, wp * a.y);
        acc.z = fmaf(acc.z, sc, wp * a.z);
        acc.w = fmaf(acc.w, sc, wp * a.w);
        ssum  = fmaf(ssum, sc, wp);
        m = nm;
    }
    const float inv = 1.0f / ssum;
    const float4 bv = *(const float4*)&bias[l * 4];
    float4 o;
    o.x = fmaxf(fmaf(acc.x, inv, bv.x), 0.f);
    o.y = fmaxf(fmaf(acc.y, inv, bv.y), 0.f);
    o.z = fmaxf(fmaf(acc.z, inv, bv.z), 0.f);
    o.w = fmaxf(fmaf(acc.w, inv, bv.w), 0.f);
    *(float4*)&out[(size_t)node * 256 + l * 4] = o;
}

// ---------------------------------------------------------------- launch
extern "C" void kernel_launch(void* const* d_in, const int* in_sizes, int n_in,
                              void* d_out, int out_size, void* d_ws, size_t ws_size,
                              hipStream_t stream) {
    const float* x    = (const float*)d_in[0];
    const int*   ei   = (const int*)d_in[1];
    const float* Wl1  = (const float*)d_in[2];
    const float* bl1  = (const float*)d_in[3];
    const float* Wr1  = (const float*)d_in[4];
    const float* br1  = (const float*)d_in[5];
    const float* att1 = (const float*)d_in[6];
    const float* bias1= (const float*)d_in[7];
    const float* Wl2  = (const float*)d_in[8];
    const float* bl2  = (const float*)d_in[9];
    const float* Wr2  = (const float*)d_in[10];
    const float* br2  = (const float*)d_in[11];
    const float* att2 = (const float*)d_in[12];
    const float* bias2= (const float*)d_in[13];
    float* out = (float*)d_out;

    const int* src = ei;            // edge_index[0]
    const int* dst = ei + E_EDGES;  // edge_index[1]

    char* ws = (char*)d_ws;
    size_t o = 0;
    auto alloc = [&](size_t bytes) -> void* {
        void* p = ws + o;
        o += (bytes + 255) & ~(size_t)255;
        return p;
    };
    float* xl      = (float*)alloc((size_t)N_NODES * HID * 4);
    float* xr      = (float*)alloc((size_t)N_NODES * HID * 4);
    float* hbuf    = (float*)alloc((size_t)N_NODES * HID * 4);
    int*   csr_src = (int*)alloc((size_t)E2 * 4);
    int*   off     = (int*)alloc((size_t)(N_NODES + 1) * 4);
    int*   deg     = (int*)alloc((size_t)N_NODES * 4);
    int*   cursor  = (int*)alloc((size_t)N_NODES * 4);
    (void)ws_size; (void)n_in; (void)in_sizes; (void)out_size;

    // CSR build (graph shared by both layers)
    k_init<<<(N_NODES + 255) / 256, 256, 0, stream>>>(deg, cursor);
    k_degree<<<(E_EDGES + 255) / 256, 256, 0, stream>>>(dst, deg);
    k_scan<<<1, 1024, 0, stream>>>(deg, off);
    k_fill<<<(E2 + 255) / 256, 256, 0, stream>>>(src, dst, off, cursor, csr_src);

    dim3 ggrid((N_NODES + 127) / 128, 8);

    // ---- layer 1
    k_gemm<<<ggrid, 256, 0, stream>>>(x, Wl1, Wr1, bl1, br1, xl, xr);
    k_edge<<<(N_NODES * 64 + 255) / 256, 256, 0, stream>>>(xl, xr, att1, csr_src, off, bias1, hbuf);

    // ---- layer 2
    k_gemm<<<ggrid, 256, 0, stream>>>(hbuf, Wl2, Wr2, bl2, br2, xl, xr);
    k_edge<<<(N_NODES * 64 + 255) / 256, 256, 0, stream>>>(xl, xr, att2, csr_src, off, bias2, out);
}

// Round 5
// 406.747 us; speedup vs baseline: 1.2492x; 1.2492x over previous
//
#include <hip/hip_runtime.h>

#define N_NODES 20000
#define E_EDGES 320000
#define E2 (E_EDGES + N_NODES)
#define HID 256
#define SLOPE 0.2f

// ---------------------------------------------------------------- CSR build
__global__ __launch_bounds__(256) void k_init(int* __restrict__ deg, int* __restrict__ cursor) {
    int i = blockIdx.x * 256 + threadIdx.x;
    if (i < N_NODES) { deg[i] = 1; cursor[i] = 0; }   // deg starts at 1: self loop
}

__global__ __launch_bounds__(256) void k_degree(const int* __restrict__ dst, int* __restrict__ deg) {
    int e = blockIdx.x * 256 + threadIdx.x;
    if (e < E_EDGES) atomicAdd(&deg[dst[e]], 1);
}

// single-block exclusive scan over deg[N] -> off[N+1]; shfl-based wave scan
__global__ __launch_bounds__(1024) void k_scan(const int* __restrict__ deg, int* __restrict__ off) {
    __shared__ int wsum[16];
    const int tid  = threadIdx.x;
    const int wave = tid >> 6;
    const int lane = tid & 63;
    int carry = 0;
    for (int base = 0; base < N_NODES; base += 1024) {
        const int i = base + tid;
        const int v = (i < N_NODES) ? deg[i] : 0;
        // inclusive scan within wave
        int x = v;
        #pragma unroll
        for (int o = 1; o < 64; o <<= 1) {
            int t = __shfl_up(x, o);
            if (lane >= o) x += t;
        }
        if (lane == 63) wsum[wave] = x;
        __syncthreads();
        if (wave == 0 && lane < 16) {
            int y = wsum[lane];
            #pragma unroll
            for (int o = 1; o < 16; o <<= 1) {
                int t = __shfl_up(y, o);
                if (lane >= o) y += t;
            }
            wsum[lane] = y;
        }
        __syncthreads();
        const int wbase = (wave == 0) ? 0 : wsum[wave - 1];
        if (i < N_NODES) off[i] = carry + wbase + (x - v);   // exclusive
        carry += wsum[15];
        __syncthreads();   // protect wsum before next iteration's writes
    }
    if (tid == 0) off[N_NODES] = carry;   // == E2
}

__global__ __launch_bounds__(256) void k_fill(const int* __restrict__ srcA, const int* __restrict__ dstA,
                                              const int* __restrict__ off, int* __restrict__ cursor,
                                              int* __restrict__ csr_src) {
    int e = blockIdx.x * 256 + threadIdx.x;
    if (e >= E2) return;
    int s, d;
    if (e < E_EDGES) { s = srcA[e]; d = dstA[e]; }
    else             { s = d = e - E_EDGES; }        // self loop
    int pos = atomicAdd(&cursor[d], 1);
    csr_src[off[d] + pos] = s;
}

// ---------------------------------------------------------------- GEMM
// X[M,256] @ {Wl|Wr}[256,256] + {bl|br} -> xl[M,256], xr[M,256]
// BM=128, BN=64, BK=32, 256 threads, 8x4 micro-tile.
// grid = (ceil(M/128), 8); by<4 -> Wl quarter, else Wr quarter.
// 25.6KB LDS; NO min-waves bound — round-4's (256,5) capped VGPR at 48 and
// spilled acc[] to scratch (WRITE_SIZE 300MB vs 41MB true output, dur +35%).
__global__ __launch_bounds__(256) void k_gemm(const float* __restrict__ X,
                                              const float* __restrict__ Wl, const float* __restrict__ Wr,
                                              const float* __restrict__ bl, const float* __restrict__ br,
                                              float* __restrict__ xl, float* __restrict__ xr) {
    __shared__ float As[32][132];   // [k][m], padded
    __shared__ float Bs[32][68];    // [k][n], padded
    const int tid = threadIdx.x;
    const int m0  = blockIdx.x * 128;
    const int by  = blockIdx.y;
    const float* W    = (by < 4) ? Wl : Wr;
    const float* bias = (by < 4) ? bl : br;
    float*       C    = (by < 4) ? xl : xr;
    const int n0 = (by & 3) * 64;
    const int tx = tid & 15;        // output cols n0 + tx*4
    const int ty = tid >> 4;        // output rows ty*4 and ty*4+64
    // A staging: each thread loads 4 rows (ar+32i), one float4 of k
    const int ar = tid >> 3;        // 0..31
    const int ac = (tid & 7) * 4;   // 0..28
    // B staging: each thread loads 2 k-rows (bkr+16i), one float4 of n
    const int bkr = tid >> 4;       // 0..15
    const int bcc = (tid & 15) * 4; // 0..60

    float4 av[4], bv[2];
#define LOAD_TILE(K0)                                                               \
    _Pragma("unroll")                                                               \
    for (int i = 0; i < 4; ++i) {                                                   \
        int gm = m0 + ar + i * 32;                                                  \
        av[i] = (gm < N_NODES)                                                      \
            ? *(const float4*)&X[(size_t)gm * 256 + (K0) + ac]                      \
            : make_float4(0.f, 0.f, 0.f, 0.f);                                      \
    }                                                                               \
    _Pragma("unroll")                                                               \
    for (int i = 0; i < 2; ++i)                                                     \
        bv[i] = *(const float4*)&W[(size_t)((K0) + bkr + i * 16) * 256 + n0 + bcc];

    LOAD_TILE(0)
    float acc[8][4] = {};
    for (int k0 = 0; k0 < 256; k0 += 32) {
        __syncthreads();   // protect previous iteration's LDS reads
        #pragma unroll
        for (int i = 0; i < 4; ++i) {
            const int mm = ar + i * 32;
            As[ac + 0][mm] = av[i].x;
            As[ac + 1][mm] = av[i].y;
            As[ac + 2][mm] = av[i].z;
            As[ac + 3][mm] = av[i].w;
        }
        #pragma unroll
        for (int i = 0; i < 2; ++i)
            *(float4*)&Bs[bkr + i * 16][bcc] = bv[i];
        __syncthreads();
        if (k0 + 32 < 256) { LOAD_TILE(k0 + 32) }   // reg prefetch of next tile

        #pragma unroll
        for (int kk = 0; kk < 32; ++kk) {
            float a8[8], b4[4];
            *(float4*)&a8[0] = *(const float4*)&As[kk][ty * 4];
            *(float4*)&a8[4] = *(const float4*)&As[kk][ty * 4 + 64];
            *(float4*)&b4[0] = *(const float4*)&Bs[kk][tx * 4];
            #pragma unroll
            for (int i = 0; i < 8; ++i)
                #pragma unroll
                for (int j = 0; j < 4; ++j)
                    acc[i][j] = fmaf(a8[i], b4[j], acc[i][j]);
        }
    }
#undef LOAD_TILE

    float4 bb4 = *(const float4*)&bias[n0 + tx * 4];
    float bb[4] = {bb4.x, bb4.y, bb4.z, bb4.w};
    #pragma unroll
    for (int half = 0; half < 2; ++half) {
        #pragma unroll
        for (int i = 0; i < 4; ++i) {
            const int gm = m0 + half * 64 + ty * 4 + i;
            if (gm < N_NODES) {
                const int ai = half * 4 + i;
                float4 o;
                o.x = acc[ai][0] + bb[0];
                o.y = acc[ai][1] + bb[1];
                o.z = acc[ai][2] + bb[2];
                o.w = acc[ai][3] + bb[3];
                *(float4*)&C[(size_t)gm * 256 + n0 + tx * 4] = o;
            }
        }
    }
}

// ---------------------------------------------------------------- fused edge phase
// one 64-lane wave per node: online-softmax over incoming edges, aggregate,
// +bias +relu. lane l covers flat channels 4l..4l+3 (head = l>>4).
// 2-deep prefetch: index fetch for p+2 overlaps row gather for p+1.
__global__ __launch_bounds__(256) void k_edge(const float* __restrict__ xl, const float* __restrict__ xr,
                                              const float* __restrict__ att,
                                              const int* __restrict__ csr_src, const int* __restrict__ off,
                                              const float* __restrict__ bias,
                                              float* __restrict__ out) {
    const int node = (blockIdx.x * 256 + threadIdx.x) >> 6;
    const int l = threadIdx.x & 63;
    if (node >= N_NODES) return;

    const float4 w  = *(const float4*)&att[l * 4];
    const float4 xd = *(const float4*)&xr[(size_t)node * 256 + l * 4];
    const int beg = off[node], end = off[node + 1];   // end > beg (self loop)

    float m = -1e30f, ssum = 0.f;
    float4 acc = make_float4(0.f, 0.f, 0.f, 0.f);

    int j1 = csr_src[beg];
    float4 a_nxt = *(const float4*)&xl[(size_t)j1 * 256 + l * 4];
    int j2 = (beg + 1 < end) ? csr_src[beg + 1] : 0;

    for (int p = beg; p < end; ++p) {
        const float4 a = a_nxt;
        if (p + 1 < end)
            a_nxt = *(const float4*)&xl[(size_t)j2 * 256 + l * 4];
        if (p + 2 < end)
            j2 = csr_src[p + 2];

        float t = 0.f, u;
        u = a.x + xd.x; u = (u > 0.f) ? u : SLOPE * u; t = fmaf(u, w.x, t);
        u = a.y + xd.y; u = (u > 0.f) ? u : SLOPE * u; t = fmaf(u, w.y, t);
        u = a.z + xd.z; u = (u > 0.f) ? u : SLOPE * u; t = fmaf(u, w.z, t);
        u = a.w + xd.w; u = (u > 0.f) ? u : SLOPE * u; t = fmaf(u, w.w, t);
        t += __shfl_xor(t, 1);
        t += __shfl_xor(t, 2);
        t += __shfl_xor(t, 4);
        t += __shfl_xor(t, 8);     // 16-lane head-group dot over 64 channels

        const float nm = fmaxf(m, t);
        const float sc = __expf(m - nm);
        const float wp = __expf(t - nm);
        acc.x = fmaf(acc.x, sc, wp * a.x);
        acc.y = fmaf(acc.y, sc, wp * a.y);
        acc.z = fmaf(acc.z, sc, wp * a.z);
        acc.w = fmaf(acc.w, sc, wp * a.w);
        ssum  = fmaf(ssum, sc, wp);
        m = nm;
    }
    const float inv = 1.0f / ssum;
    const float4 bv = *(const float4*)&bias[l * 4];
    float4 o;
    o.x = fmaxf(fmaf(acc.x, inv, bv.x), 0.f);
    o.y = fmaxf(fmaf(acc.y, inv, bv.y), 0.f);
    o.z = fmaxf(fmaf(acc.z, inv, bv.z), 0.f);
    o.w = fmaxf(fmaf(acc.w, inv, bv.w), 0.f);
    *(float4*)&out[(size_t)node * 256 + l * 4] = o;
}

// ---------------------------------------------------------------- launch
extern "C" void kernel_launch(void* const* d_in, const int* in_sizes, int n_in,
                              void* d_out, int out_size, void* d_ws, size_t ws_size,
                              hipStream_t stream) {
    const float* x    = (const float*)d_in[0];
    const int*   ei   = (const int*)d_in[1];
    const float* Wl1  = (const float*)d_in[2];
    const float* bl1  = (const float*)d_in[3];
    const float* Wr1  = (const float*)d_in[4];
    const float* br1  = (const float*)d_in[5];
    const float* att1 = (const float*)d_in[6];
    const float* bias1= (const float*)d_in[7];
    const float* Wl2  = (const float*)d_in[8];
    const float* bl2  = (const float*)d_in[9];
    const float* Wr2  = (const float*)d_in[10];
    const float* br2  = (const float*)d_in[11];
    const float* att2 = (const float*)d_in[12];
    const float* bias2= (const float*)d_in[13];
    float* out = (float*)d_out;

    const int* src = ei;            // edge_index[0]
    const int* dst = ei + E_EDGES;  // edge_index[1]

    char* ws = (char*)d_ws;
    size_t o = 0;
    auto alloc = [&](size_t bytes) -> void* {
        void* p = ws + o;
        o += (bytes + 255) & ~(size_t)255;
        return p;
    };
    float* xl      = (float*)alloc((size_t)N_NODES * HID * 4);
    float* xr      = (float*)alloc((size_t)N_NODES * HID * 4);
    float* hbuf    = (float*)alloc((size_t)N_NODES * HID * 4);
    int*   csr_src = (int*)alloc((size_t)E2 * 4);
    int*   off     = (int*)alloc((size_t)(N_NODES + 1) * 4);
    int*   deg     = (int*)alloc((size_t)N_NODES * 4);
    int*   cursor  = (int*)alloc((size_t)N_NODES * 4);
    (void)ws_size; (void)n_in; (void)in_sizes; (void)out_size;

    // CSR build (graph shared by both layers)
    k_init<<<(N_NODES + 255) / 256, 256, 0, stream>>>(deg, cursor);
    k_degree<<<(E_EDGES + 255) / 256, 256, 0, stream>>>(dst, deg);
    k_scan<<<1, 1024, 0, stream>>>(deg, off);
    k_fill<<<(E2 + 255) / 256, 256, 0, stream>>>(src, dst, off, cursor, csr_src);

    dim3 ggrid((N_NODES + 127) / 128, 8);

    // ---- layer 1
    k_gemm<<<ggrid, 256, 0, stream>>>(x, Wl1, Wr1, bl1, br1, xl, xr);
    k_edge<<<(N_NODES * 64 + 255) / 256, 256, 0, stream>>>(xl, xr, att1, csr_src, off, bias1, hbuf);

    // ---- layer 2
    k_gemm<<<ggrid, 256, 0, stream>>>(hbuf, Wl2, Wr2, bl2, br2, xl, xr);
    k_edge<<<(N_NODES * 64 + 255) / 256, 256, 0, stream>>>(xl, xr, att2, csr_src, off, bias2, out);
}

// Round 6
// 399.218 us; speedup vs baseline: 1.2727x; 1.0189x over previous
//
#include <hip/hip_runtime.h>

#define N_NODES 20000
#define E_EDGES 320000
#define E2 (E_EDGES + N_NODES)
#define HID 256
#define SLOPE 0.2f

// ---------------------------------------------------------------- CSR build
__global__ __launch_bounds__(256) void k_init(int* __restrict__ deg, int* __restrict__ cursor) {
    int i = blockIdx.x * 256 + threadIdx.x;
    if (i < N_NODES) { deg[i] = 1; cursor[i] = 0; }   // deg starts at 1: self loop
}

__global__ __launch_bounds__(256) void k_degree(const int* __restrict__ dst, int* __restrict__ deg) {
    int e = blockIdx.x * 256 + threadIdx.x;
    if (e < E_EDGES) atomicAdd(&deg[dst[e]], 1);
}

// single-block exclusive scan over deg[N] -> off[N+1]; shfl-based wave scan
__global__ __launch_bounds__(1024) void k_scan(const int* __restrict__ deg, int* __restrict__ off) {
    __shared__ int wsum[16];
    const int tid  = threadIdx.x;
    const int wave = tid >> 6;
    const int lane = tid & 63;
    int carry = 0;
    for (int base = 0; base < N_NODES; base += 1024) {
        const int i = base + tid;
        const int v = (i < N_NODES) ? deg[i] : 0;
        // inclusive scan within wave
        int x = v;
        #pragma unroll
        for (int o = 1; o < 64; o <<= 1) {
            int t = __shfl_up(x, o);
            if (lane >= o) x += t;
        }
        if (lane == 63) wsum[wave] = x;
        __syncthreads();
        if (wave == 0 && lane < 16) {
            int y = wsum[lane];
            #pragma unroll
            for (int o = 1; o < 16; o <<= 1) {
                int t = __shfl_up(y, o);
                if (lane >= o) y += t;
            }
            wsum[lane] = y;
        }
        __syncthreads();
        const int wbase = (wave == 0) ? 0 : wsum[wave - 1];
        if (i < N_NODES) off[i] = carry + wbase + (x - v);   // exclusive
        carry += wsum[15];
        __syncthreads();   // protect wsum before next iteration's writes
    }
    if (tid == 0) off[N_NODES] = carry;   // == E2
}

__global__ __launch_bounds__(256) void k_fill(const int* __restrict__ srcA, const int* __restrict__ dstA,
                                              const int* __restrict__ off, int* __restrict__ cursor,
                                              int* __restrict__ csr_src) {
    int e = blockIdx.x * 256 + threadIdx.x;
    if (e >= E2) return;
    int s, d;
    if (e < E_EDGES) { s = srcA[e]; d = dstA[e]; }
    else             { s = d = e - E_EDGES; }        // self loop
    int pos = atomicAdd(&cursor[d], 1);
    csr_src[off[d] + pos] = s;
}

// ---------------------------------------------------------------- GEMM
// X[M,256] @ {Wl|Wr}[256,256] + {bl|br} -> xl[M,256], xr[M,256]
// BM=128, BN=64, BK=32, 256 threads, 8x4 micro-tile.
// grid = (ceil(M/128), 8); by<4 -> Wl quarter, else Wr quarter.
// NO register prefetch: the held av/bv (24 VGPR across the compute loop)
// pushed the working set past the allocator's self-chosen 64-VGPR budget
// (r5: WRITE_SIZE 80MB vs 41MB true -> ~39MB spill). Working set now fits
// 64 VGPR; latency hiding comes from TLP (25.6KB LDS -> 6 blocks/CU,
// grid 1256 on 1536 slots = near-全-resident).
__global__ __launch_bounds__(256) void k_gemm(const float* __restrict__ X,
                                              const float* __restrict__ Wl, const float* __restrict__ Wr,
                                              const float* __restrict__ bl, const float* __restrict__ br,
                                              float* __restrict__ xl, float* __restrict__ xr) {
    __shared__ float As[32][132];   // [k][m], padded
    __shared__ float Bs[32][68];    // [k][n], padded
    const int tid = threadIdx.x;
    const int m0  = blockIdx.x * 128;
    const int by  = blockIdx.y;
    const float* W    = (by < 4) ? Wl : Wr;
    const float* bias = (by < 4) ? bl : br;
    float*       C    = (by < 4) ? xl : xr;
    const int n0 = (by & 3) * 64;
    const int tx = tid & 15;        // output cols n0 + tx*4
    const int ty = tid >> 4;        // output rows ty*4 and ty*4+64
    // A staging: each thread loads 4 rows (ar+32i), one float4 of k
    const int ar = tid >> 3;        // 0..31
    const int ac = (tid & 7) * 4;   // 0..28
    // B staging: each thread loads 2 k-rows (bkr+16i), one float4 of n
    const int bkr = tid >> 4;       // 0..15
    const int bcc = (tid & 15) * 4; // 0..60

    float acc[8][4] = {};
    for (int k0 = 0; k0 < 256; k0 += 32) {
        float4 av[4], bv[2];
        #pragma unroll
        for (int i = 0; i < 4; ++i) {
            const int gm = m0 + ar + i * 32;
            av[i] = (gm < N_NODES)
                ? *(const float4*)&X[(size_t)gm * 256 + k0 + ac]
                : make_float4(0.f, 0.f, 0.f, 0.f);
        }
        #pragma unroll
        for (int i = 0; i < 2; ++i)
            bv[i] = *(const float4*)&W[(size_t)(k0 + bkr + i * 16) * 256 + n0 + bcc];

        __syncthreads();   // protect previous iteration's LDS reads
        #pragma unroll
        for (int i = 0; i < 4; ++i) {
            const int mm = ar + i * 32;
            As[ac + 0][mm] = av[i].x;
            As[ac + 1][mm] = av[i].y;
            As[ac + 2][mm] = av[i].z;
            As[ac + 3][mm] = av[i].w;
        }
        #pragma unroll
        for (int i = 0; i < 2; ++i)
            *(float4*)&Bs[bkr + i * 16][bcc] = bv[i];
        __syncthreads();

        #pragma unroll
        for (int kk = 0; kk < 32; ++kk) {
            float a8[8], b4[4];
            *(float4*)&a8[0] = *(const float4*)&As[kk][ty * 4];
            *(float4*)&a8[4] = *(const float4*)&As[kk][ty * 4 + 64];
            *(float4*)&b4[0] = *(const float4*)&Bs[kk][tx * 4];
            #pragma unroll
            for (int i = 0; i < 8; ++i)
                #pragma unroll
                for (int j = 0; j < 4; ++j)
                    acc[i][j] = fmaf(a8[i], b4[j], acc[i][j]);
        }
    }

    float4 bb4 = *(const float4*)&bias[n0 + tx * 4];
    float bb[4] = {bb4.x, bb4.y, bb4.z, bb4.w};
    #pragma unroll
    for (int half = 0; half < 2; ++half) {
        #pragma unroll
        for (int i = 0; i < 4; ++i) {
            const int gm = m0 + half * 64 + ty * 4 + i;
            if (gm < N_NODES) {
                const int ai = half * 4 + i;
                float4 o;
                o.x = acc[ai][0] + bb[0];
                o.y = acc[ai][1] + bb[1];
                o.z = acc[ai][2] + bb[2];
                o.w = acc[ai][3] + bb[3];
                *(float4*)&C[(size_t)gm * 256 + n0 + tx * 4] = o;
            }
        }
    }
}

// ---------------------------------------------------------------- fused edge phase
// one 64-lane wave per node: online-softmax over incoming edges, aggregate,
// +bias +relu. lane l covers flat channels 4l..4l+3 (head = l>>4).
// 2-deep prefetch: index fetch for p+2 overlaps row gather for p+1.
__global__ __launch_bounds__(256) void k_edge(const float* __restrict__ xl, const float* __restrict__ xr,
                                              const float* __restrict__ att,
                                              const int* __restrict__ csr_src, const int* __restrict__ off,
                                              const float* __restrict__ bias,
                                              float* __restrict__ out) {
    const int node = (blockIdx.x * 256 + threadIdx.x) >> 6;
    const int l = threadIdx.x & 63;
    if (node >= N_NODES) return;

    const float4 w  = *(const float4*)&att[l * 4];
    const float4 xd = *(const float4*)&xr[(size_t)node * 256 + l * 4];
    const int beg = off[node], end = off[node + 1];   // end > beg (self loop)

    float m = -1e30f, ssum = 0.f;
    float4 acc = make_float4(0.f, 0.f, 0.f, 0.f);

    int j1 = csr_src[beg];
    float4 a_nxt = *(const float4*)&xl[(size_t)j1 * 256 + l * 4];
    int j2 = (beg + 1 < end) ? csr_src[beg + 1] : 0;

    for (int p = beg; p < end; ++p) {
        const float4 a = a_nxt;
        if (p + 1 < end)
            a_nxt = *(const float4*)&xl[(size_t)j2 * 256 + l * 4];
        if (p + 2 < end)
            j2 = csr_src[p + 2];

        float t = 0.f, u;
        u = a.x + xd.x; u = (u > 0.f) ? u : SLOPE * u; t = fmaf(u, w.x, t);
        u = a.y + xd.y; u = (u > 0.f) ? u : SLOPE * u; t = fmaf(u, w.y, t);
        u = a.z + xd.z; u = (u > 0.f) ? u : SLOPE * u; t = fmaf(u, w.z, t);
        u = a.w + xd.w; u = (u > 0.f) ? u : SLOPE * u; t = fmaf(u, w.w, t);
        t += __shfl_xor(t, 1);
        t += __shfl_xor(t, 2);
        t += __shfl_xor(t, 4);
        t += __shfl_xor(t, 8);     // 16-lane head-group dot over 64 channels

        const float nm = fmaxf(m, t);
        const float sc = __expf(m - nm);
        const float wp = __expf(t - nm);
        acc.x = fmaf(acc.x, sc, wp * a.x);
        acc.y = fmaf(acc.y, sc, wp * a.y);
        acc.z = fmaf(acc.z, sc, wp * a.z);
        acc.w = fmaf(acc.w, sc, wp * a.w);
        ssum  = fmaf(ssum, sc, wp);
        m = nm;
    }
    const float inv = 1.0f / ssum;
    const float4 bv = *(const float4*)&bias[l * 4];
    float4 o;
    o.x = fmaxf(fmaf(acc.x, inv, bv.x), 0.f);
    o.y = fmaxf(fmaf(acc.y, inv, bv.y), 0.f);
    o.z = fmaxf(fmaf(acc.z, inv, bv.z), 0.f);
    o.w = fmaxf(fmaf(acc.w, inv, bv.w), 0.f);
    *(float4*)&out[(size_t)node * 256 + l * 4] = o;
}

// ---------------------------------------------------------------- launch
extern "C" void kernel_launch(void* const* d_in, const int* in_sizes, int n_in,
                              void* d_out, int out_size, void* d_ws, size_t ws_size,
                              hipStream_t stream) {
    const float* x    = (const float*)d_in[0];
    const int*   ei   = (const int*)d_in[1];
    const float* Wl1  = (const float*)d_in[2];
    const float* bl1  = (const float*)d_in[3];
    const float* Wr1  = (const float*)d_in[4];
    const float* br1  = (const float*)d_in[5];
    const float* att1 = (const float*)d_in[6];
    const float* bias1= (const float*)d_in[7];
    const float* Wl2  = (const float*)d_in[8];
    const float* bl2  = (const float*)d_in[9];
    const float* Wr2  = (const float*)d_in[10];
    const float* br2  = (const float*)d_in[11];
    const float* att2 = (const float*)d_in[12];
    const float* bias2= (const float*)d_in[13];
    float* out = (float*)d_out;

    const int* src = ei;            // edge_index[0]
    const int* dst = ei + E_EDGES;  // edge_index[1]

    char* ws = (char*)d_ws;
    size_t o = 0;
    auto alloc = [&](size_t bytes) -> void* {
        void* p = ws + o;
        o += (bytes + 255) & ~(size_t)255;
        return p;
    };
    float* xl      = (float*)alloc((size_t)N_NODES * HID * 4);
    float* xr      = (float*)alloc((size_t)N_NODES * HID * 4);
    float* hbuf    = (float*)alloc((size_t)N_NODES * HID * 4);
    int*   csr_src = (int*)alloc((size_t)E2 * 4);
    int*   off     = (int*)alloc((size_t)(N_NODES + 1) * 4);
    int*   deg     = (int*)alloc((size_t)N_NODES * 4);
    int*   cursor  = (int*)alloc((size_t)N_NODES * 4);
    (void)ws_size; (void)n_in; (void)in_sizes; (void)out_size;

    // CSR build (graph shared by both layers)
    k_init<<<(N_NODES + 255) / 256, 256, 0, stream>>>(deg, cursor);
    k_degree<<<(E_EDGES + 255) / 256, 256, 0, stream>>>(dst, deg);
    k_scan<<<1, 1024, 0, stream>>>(deg, off);
    k_fill<<<(E2 + 255) / 256, 256, 0, stream>>>(src, dst, off, cursor, csr_src);

    dim3 ggrid((N_NODES + 127) / 128, 8);

    // ---- layer 1
    k_gemm<<<ggrid, 256, 0, stream>>>(x, Wl1, Wr1, bl1, br1, xl, xr);
    k_edge<<<(N_NODES * 64 + 255) / 256, 256, 0, stream>>>(xl, xr, att1, csr_src, off, bias1, hbuf);

    // ---- layer 2
    k_gemm<<<ggrid, 256, 0, stream>>>(hbuf, Wl2, Wr2, bl2, br2, xl, xr);
    k_edge<<<(N_NODES * 64 + 255) / 256, 256, 0, stream>>>(xl, xr, att2, csr_src, off, bias2, out);
}